// Round 9
// baseline (643.407 us; speedup 1.0000x reference)
//
#include <hip/hip_runtime.h>
#include <hip/hip_bf16.h>

#define NROW 8192
#define DDIM 1024          // bytes per fp8 row
#define TINV 2.0f          // 1 / TEMPERATURE
#define SCALE1 0x7F7F7F7F  // e8m0 = 127 in every byte -> scale 1.0

typedef __attribute__((ext_vector_type(4))) float f32x4;
typedef __attribute__((ext_vector_type(4))) int   i32x4;
typedef __attribute__((ext_vector_type(8))) int   i32x8;

union frag8 { i32x8 v8; i32x4 v4[2]; };   // ds_read_b128 lands directly in
                                          // MFMA operand halves (no copies)

__device__ __forceinline__ void gload_lds16(const void* g, void* l) {
  __builtin_amdgcn_global_load_lds(
      (const __attribute__((address_space(1))) void*)g,
      (__attribute__((address_space(3))) void*)l, 16, 0, 0);
}

#define SBAR()  __builtin_amdgcn_s_barrier()
#define PRIO(x) __builtin_amdgcn_s_setprio(x)
#define VMCNT(N) asm volatile("s_waitcnt vmcnt(" #N ")" ::: "memory")

// ---- manual f32 -> fp8 e4m3fn (OCP), RNE, saturating ----
__device__ __forceinline__ unsigned f2fp8(float x) {
  unsigned b = __float_as_uint(x);
  unsigned sgn = (b >> 24) & 0x80u;
  float af = __uint_as_float(b & 0x7FFFFFFFu);
  if (af >= 448.0f) return sgn | 0x7Eu;
  if (af < 0.015625f) {
    unsigned q = (unsigned)__float2int_rn(af * 512.0f);
    return sgn | q;
  }
  unsigned ab = b & 0x7FFFFFFFu;
  unsigned m  = ab & 0x7FFFFFu;
  unsigned m3 = m >> 20;
  unsigned rem = m & 0xFFFFFu;
  unsigned rnd = (rem > 0x80000u) || (rem == 0x80000u && (m3 & 1u));
  unsigned e  = (ab >> 23) - 120u;
  return sgn | ((e << 3) + m3 + rnd);
}

// ---------------------------------------------------------------------------
// Kernel 1: per-row L2 norms, diag (fp32-exact), fp8 normalized copies
// (z1 pre-scaled by 1/T; power-of-2 scale = exact).
// ---------------------------------------------------------------------------
__global__ __launch_bounds__(256) void normalize_diag(
    const float* __restrict__ v1, const float* __restrict__ v2,
    unsigned* __restrict__ z1, unsigned* __restrict__ z2,
    float* __restrict__ diag)
{
  const int row = blockIdx.x;
  const int t = threadIdx.x;
  const float4 a = ((const float4*)(v1 + (size_t)row * 1024))[t];
  const float4 b = ((const float4*)(v2 + (size_t)row * 1024))[t];
  float s1 = a.x*a.x + a.y*a.y + a.z*a.z + a.w*a.w;
  float s2 = b.x*b.x + b.y*b.y + b.z*b.z + b.w*b.w;
  float sd = a.x*b.x + a.y*b.y + a.z*b.z + a.w*b.w;
  #pragma unroll
  for (int m = 1; m < 64; m <<= 1) {
    s1 += __shfl_xor(s1, m);
    s2 += __shfl_xor(s2, m);
    sd += __shfl_xor(sd, m);
  }
  __shared__ float red[3][4];
  const int w = t >> 6;
  if ((t & 63) == 0) { red[0][w] = s1; red[1][w] = s2; red[2][w] = sd; }
  __syncthreads();
  s1 = red[0][0] + red[0][1] + red[0][2] + red[0][3];
  s2 = red[1][0] + red[1][1] + red[1][2] + red[1][3];
  sd = red[2][0] + red[2][1] + red[2][2] + red[2][3];
  const float i1 = 1.0f / fmaxf(sqrtf(s1), 1e-12f);
  const float i2 = 1.0f / fmaxf(sqrtf(s2), 1e-12f);
  if (t == 0) diag[row] = sd * i1 * i2 * TINV;
  const float sc1 = i1 * TINV;
  unsigned o1 = f2fp8(a.x*sc1) | (f2fp8(a.y*sc1) << 8)
              | (f2fp8(a.z*sc1) << 16) | (f2fp8(a.w*sc1) << 24);
  unsigned o2 = f2fp8(b.x*i2)  | (f2fp8(b.y*i2)  << 8)
              | (f2fp8(b.z*i2) << 16) | (f2fp8(b.w*i2)  << 24);
  z1[(size_t)row * 256 + t] = o1;
  z2[(size_t)row * 256 + t] = o2;
}

// ---------------------------------------------------------------------------
// Kernel 2: 256x256-tile MX-fp8 GEMM (sim = z1*z2^T) + fused exp-rowsum.
// Identical schedule to R8 (race-free 4-phase, counted VMCNT(8), setprio,
// 0-conflict b128 geometry, unit scales) with the register-pressure fixes:
// union-aliased fragments (no assembly copies) and no outer unroll.
// ---------------------------------------------------------------------------
#define BM 256
#define BN 256
#define BK 128
#define KTILES (DDIM / BK)

__global__ __launch_bounds__(512, 2) void gemm_rowsum(
    const unsigned char* __restrict__ z1b,
    const unsigned char* __restrict__ z2b,
    float* __restrict__ partial)
{
  __shared__ __align__(16) unsigned char As[2][BM * BK];   // 2 x 32 KiB
  __shared__ __align__(16) unsigned char Bs[2][BN * BK];   // 2 x 32 KiB

  const int bid = blockIdx.x;
  const int bi = bid >> 5;          // 32 row-blocks
  const int bj = bid & 31;          // 32 col-blocks
  const int brow = bi * BM;
  const int bcol = bj * BN;
  const int t = threadIdx.x;
  const int w = t >> 6;             // wave 0..7
  const int lane = t & 63;
  const int wr = w >> 2;            // 0..1: A rows wr*128
  const int wc = w & 3;             // 0..3: B cols wc*64
  const int lcol = lane & 15;
  const int lgrp = lane >> 4;       // 0..3
  const int l7 = lcol & 7;
  const int sr = lane >> 3;         // stage: row within 8-row slab (0..7)
  const int sc = lane & 7;          // stage: 16B chunk (0..7)
  const int ssw = (sc ^ sr) << 4;   // pre-swizzled global byte offset

  f32x4 acc[8][4];
  #pragma unroll
  for (int i = 0; i < 8; ++i)
    #pragma unroll
    for (int j = 0; j < 4; ++j)
      acc[i][j] = (f32x4){0.f, 0.f, 0.f, 0.f};

  // ---- staging: slab = 8 rows x 128B = 1KB per gload; 4 A + 4 B per wave
#define STAGE_A(S, BUF, K0)                                                   \
  gload_lds16(z1b + (size_t)(brow + (w*4 + (S))*8 + sr) * DDIM + (K0) + ssw,  \
              &As[BUF][(w*4 + (S)) * 1024])
#define STAGE_B(S, BUF, K0)                                                   \
  gload_lds16(z2b + (size_t)(bcol + (w*4 + (S))*8 + sr) * DDIM + (K0) + ssw,  \
              &Bs[BUF][(w*4 + (S)) * 1024])

  // ---- fragment read: two b128 straight into the operand's halves ----
#define RDFRAG(DST, ARR, ROWB)                                                \
  do {                                                                        \
    const int rb_ = (ROWB);                                                   \
    DST.v4[0] = *(const i32x4*)&ARR[rb_*128 + ((lgrp)     ^ l7)*16];          \
    DST.v4[1] = *(const i32x4*)&ARR[rb_*128 + ((4 + lgrp) ^ l7)*16];          \
  } while (0)

#define RA(MT, BUF, DST) RDFRAG(DST, As[BUF], wr*128 + (MT)*16 + lcol)
#define RB(NT, BUF, DST) RDFRAG(DST, Bs[BUF], wc*64  + (NT)*16 + lcol)

#define MF(MT, NT, AA, BB)                                                    \
  acc[MT][NT] = __builtin_amdgcn_mfma_scale_f32_16x16x128_f8f6f4(             \
      AA.v8, BB.v8, acc[MT][NT], 0, 0, 0, SCALE1, 0, SCALE1)

  // prologue: stage tile 0 -> buf0, tile 1 -> buf1; counted wait for tile 0
  #pragma unroll
  for (int s = 0; s < 4; ++s) { STAGE_A(s, 0, 0); STAGE_B(s, 0, 0); }
  #pragma unroll
  for (int s = 0; s < 4; ++s) { STAGE_A(s, 1, BK); STAGE_B(s, 1, BK); }
  VMCNT(8);          // tile 0's 8 loads landed; tile 1's stay in flight
  SBAR();

  frag8 am[4], bn0, bn1, bn2, bn3;

  for (int kt = 0; kt < KTILES; ++kt) {
    const int cur = kt & 1;
    const int k2 = (kt + 2) * BK;
    const bool pf2 = (kt + 2 < KTILES);

    // ---- P1: read A m0..3 (8 b128) + B n0,n1 (4 b128); 8 MFMA ----
    #pragma unroll
    for (int mi = 0; mi < 4; ++mi) RA(mi, cur, am[mi]);
    RB(0, cur, bn0); RB(1, cur, bn1);
    SBAR();
    PRIO(1);
    MF(0,0,am[0],bn0); MF(1,1,am[1],bn1); MF(2,0,am[2],bn0); MF(3,1,am[3],bn1);
    MF(0,1,am[0],bn1); MF(1,0,am[1],bn0); MF(2,1,am[2],bn1); MF(3,0,am[3],bn0);
    PRIO(0);
    SBAR();

    // ---- P2: read B n2,n3 (last Bs[cur] reads); 8 MFMA ----
    RB(2, cur, bn2); RB(3, cur, bn3);
    SBAR();
    PRIO(1);
    MF(0,2,am[0],bn2); MF(1,3,am[1],bn3); MF(2,2,am[2],bn2); MF(3,3,am[3],bn3);
    MF(0,3,am[0],bn3); MF(1,2,am[1],bn2); MF(2,3,am[2],bn3); MF(3,2,am[3],bn2);
    PRIO(0);
    SBAR();

    // ---- P3: read A m4..7 (last As[cur] reads); stage next-next B
    //      (Bs[cur] drained: consumed by P2 MFMA + barrier) ----
    #pragma unroll
    for (int mi = 0; mi < 4; ++mi) RA(mi + 4, cur, am[mi]);
    if (pf2) { STAGE_B(0, cur, k2); STAGE_B(1, cur, k2);
               STAGE_B(2, cur, k2); STAGE_B(3, cur, k2); }
    SBAR();
    PRIO(1);
    MF(4,2,am[0],bn2); MF(5,3,am[1],bn3); MF(6,2,am[2],bn2); MF(7,3,am[3],bn3);
    MF(4,3,am[0],bn3); MF(5,2,am[1],bn2); MF(6,3,am[2],bn3); MF(7,2,am[3],bn2);
    PRIO(0);
    SBAR();

    // ---- P4: stage next-next A (As[cur] drained by P3 MFMA + barrier);
    //      8 MFMA; counted tile-boundary wait ----
    if (pf2) { STAGE_A(0, cur, k2); STAGE_A(1, cur, k2);
               STAGE_A(2, cur, k2); STAGE_A(3, cur, k2); }
    PRIO(1);
    MF(4,0,am[0],bn0); MF(5,1,am[1],bn1); MF(6,0,am[2],bn0); MF(7,1,am[3],bn1);
    MF(4,1,am[0],bn1); MF(5,0,am[1],bn0); MF(6,1,am[2],bn1); MF(7,0,am[3],bn0);
    PRIO(0);
    if (pf2)                   VMCNT(8);   // kt+1 ready; kt+2 in flight
    else if (kt + 1 < KTILES)  VMCNT(0);   // kt==KTILES-2: drain last tile
    SBAR();
  }

  // ---- epilogue: exp + per-row sum over this block's 256 cols ----
  // C/D layout (shape-determined): col = lane&15, row = lgrp*4 + reg.
  float* rs = (float*)&As[0][0];   // [4][256] f32, aliased (loads drained)
  #pragma unroll
  for (int mt = 0; mt < 8; ++mt) {
    #pragma unroll
    for (int r = 0; r < 4; ++r) {
      float s = __expf(acc[mt][0][r]) + __expf(acc[mt][1][r])
              + __expf(acc[mt][2][r]) + __expf(acc[mt][3][r]);
      s += __shfl_xor(s, 1);
      s += __shfl_xor(s, 2);
      s += __shfl_xor(s, 4);
      s += __shfl_xor(s, 8);
      if (lcol == 0)
        rs[wc * 256 + wr * 128 + mt * 16 + lgrp * 4 + r] = s;
    }
  }
  __syncthreads();
  if (t < 256)
    partial[(size_t)bj * NROW + brow + t] =
        rs[t] + rs[256 + t] + rs[512 + t] + rs[768 + t];
}

// ---------------------------------------------------------------------------
// Kernel 3: per-row loss = log(sum of 32 partials) - diag; block partial sums.
// ---------------------------------------------------------------------------
__global__ __launch_bounds__(256) void rowloss(
    const float* __restrict__ partial, const float* __restrict__ diag,
    float* __restrict__ blocksum)
{
  const int i = blockIdx.x * 256 + threadIdx.x;
  float s = 0.f;
  #pragma unroll 8
  for (int b = 0; b < 32; ++b) s += partial[(size_t)b * NROW + i];
  float loss = logf(s) - diag[i];
  #pragma unroll
  for (int m = 1; m < 64; m <<= 1) loss += __shfl_xor(loss, m);
  __shared__ float red[4];
  if ((threadIdx.x & 63) == 0) red[threadIdx.x >> 6] = loss;
  __syncthreads();
  if (threadIdx.x == 0)
    blocksum[blockIdx.x] = red[0] + red[1] + red[2] + red[3];
}

__global__ void finalize(const float* __restrict__ blocksum,
                         float* __restrict__ out)
{
  float s = (threadIdx.x < 32) ? blocksum[threadIdx.x] : 0.f;
  #pragma unroll
  for (int m = 1; m < 64; m <<= 1) s += __shfl_xor(s, m);
  if (threadIdx.x == 0) out[0] = s * (1.0f / NROW);
}

// ---------------------------------------------------------------------------
extern "C" void kernel_launch(void* const* d_in, const int* in_sizes, int n_in,
                              void* d_out, int out_size, void* d_ws, size_t ws_size,
                              hipStream_t stream) {
  const float* v1 = (const float*)d_in[0];
  const float* v2 = (const float*)d_in[1];
  float* out = (float*)d_out;

  char* ws = (char*)d_ws;
  // layout: z1 (8MB fp8) | z2 (8MB fp8) | diag (32KB) | partial (1MB) | bsum
  unsigned char* z1 = (unsigned char*)ws;
  unsigned char* z2 = (unsigned char*)(ws + (size_t)NROW * DDIM);
  float* diag = (float*)(ws + (size_t)NROW * DDIM * 2);
  float* partial = (float*)(ws + (size_t)NROW * DDIM * 2 + (size_t)NROW * 4);
  float* blocksum = (float*)(ws + (size_t)NROW * DDIM * 2 + (size_t)NROW * 4
                             + (size_t)32 * NROW * 4);

  normalize_diag<<<NROW, 256, 0, stream>>>(v1, v2, (unsigned*)z1, (unsigned*)z2,
                                           diag);
  gemm_rowsum<<<(NROW / BM) * (NROW / BN), 512, 0, stream>>>(z1, z2, partial);
  rowloss<<<NROW / 256, 256, 0, stream>>>(partial, diag, blocksum);
  finalize<<<1, 64, 0, stream>>>(blocksum, out);
}

// Round 10
// 409.669 us; speedup vs baseline: 1.5706x; 1.5706x over previous
//
#include <hip/hip_runtime.h>
#include <hip/hip_bf16.h>

#define NROW 8192
#define DDIM 1024          // bytes per fp8 row
#define TINV 2.0f          // 1 / TEMPERATURE
#define SCALE1 0x7F7F7F7F  // e8m0 = 127 in every byte -> scale 1.0

typedef __attribute__((ext_vector_type(4))) float f32x4;
typedef __attribute__((ext_vector_type(4))) int   i32x4;
typedef __attribute__((ext_vector_type(8))) int   i32x8;

__device__ __forceinline__ void gload_lds16(const void* g, void* l) {
  __builtin_amdgcn_global_load_lds(
      (const __attribute__((address_space(1))) void*)g,
      (__attribute__((address_space(3))) void*)l, 16, 0, 0);
}

#define SBAR()  __builtin_amdgcn_s_barrier()
#define PRIO(x) __builtin_amdgcn_s_setprio(x)
#define VMCNT(N) asm volatile("s_waitcnt vmcnt(" #N ")" ::: "memory")

// ---- manual f32 -> fp8 e4m3fn (OCP), RNE, saturating ----
__device__ __forceinline__ unsigned f2fp8(float x) {
  unsigned b = __float_as_uint(x);
  unsigned sgn = (b >> 24) & 0x80u;
  float af = __uint_as_float(b & 0x7FFFFFFFu);
  if (af >= 448.0f) return sgn | 0x7Eu;
  if (af < 0.015625f) {
    unsigned q = (unsigned)__float2int_rn(af * 512.0f);
    return sgn | q;
  }
  unsigned ab = b & 0x7FFFFFFFu;
  unsigned m  = ab & 0x7FFFFFu;
  unsigned m3 = m >> 20;
  unsigned rem = m & 0xFFFFFu;
  unsigned rnd = (rem > 0x80000u) || (rem == 0x80000u && (m3 & 1u));
  unsigned e  = (ab >> 23) - 120u;
  return sgn | ((e << 3) + m3 + rnd);
}

// ---------------------------------------------------------------------------
// Kernel 1: per-row L2 norms, diag (fp32-exact), fp8 normalized copies
// (z1 pre-scaled by 1/T; power-of-2 scale = exact).
// ---------------------------------------------------------------------------
__global__ __launch_bounds__(256) void normalize_diag(
    const float* __restrict__ v1, const float* __restrict__ v2,
    unsigned* __restrict__ z1, unsigned* __restrict__ z2,
    float* __restrict__ diag)
{
  const int row = blockIdx.x;
  const int t = threadIdx.x;
  const float4 a = ((const float4*)(v1 + (size_t)row * 1024))[t];
  const float4 b = ((const float4*)(v2 + (size_t)row * 1024))[t];
  float s1 = a.x*a.x + a.y*a.y + a.z*a.z + a.w*a.w;
  float s2 = b.x*b.x + b.y*b.y + b.z*b.z + b.w*b.w;
  float sd = a.x*b.x + a.y*b.y + a.z*b.z + a.w*b.w;
  #pragma unroll
  for (int m = 1; m < 64; m <<= 1) {
    s1 += __shfl_xor(s1, m);
    s2 += __shfl_xor(s2, m);
    sd += __shfl_xor(sd, m);
  }
  __shared__ float red[3][4];
  const int w = t >> 6;
  if ((t & 63) == 0) { red[0][w] = s1; red[1][w] = s2; red[2][w] = sd; }
  __syncthreads();
  s1 = red[0][0] + red[0][1] + red[0][2] + red[0][3];
  s2 = red[1][0] + red[1][1] + red[1][2] + red[1][3];
  sd = red[2][0] + red[2][1] + red[2][2] + red[2][3];
  const float i1 = 1.0f / fmaxf(sqrtf(s1), 1e-12f);
  const float i2 = 1.0f / fmaxf(sqrtf(s2), 1e-12f);
  if (t == 0) diag[row] = sd * i1 * i2 * TINV;
  const float sc1 = i1 * TINV;
  unsigned o1 = f2fp8(a.x*sc1) | (f2fp8(a.y*sc1) << 8)
              | (f2fp8(a.z*sc1) << 16) | (f2fp8(a.w*sc1) << 24);
  unsigned o2 = f2fp8(b.x*i2)  | (f2fp8(b.y*i2)  << 8)
              | (f2fp8(b.z*i2) << 16) | (f2fp8(b.w*i2)  << 24);
  z1[(size_t)row * 256 + t] = o1;
  z2[(size_t)row * 256 + t] = o2;
}

// ---------------------------------------------------------------------------
// Kernel 2: 256x128-tile MX-fp8 GEMM (sim = z1*z2^T) + fused exp-rowsum.
// mfma_scale needs VGPR-only working set (no AGPR relief observed R8/R9),
// so per-wave acc is capped at 64 regs: 8 waves in a 4x2 grid, 64x64 each.
// BK=128 bytes, 2-buffer LDS = 96 KiB, 1 block/CU, grid 2048 = 8 rounds.
// R7's proven per-wave register envelope (acc 64 + am 32 + bn 32), R7's
// race-free staging discipline (stage a region >=2 barriers after its last
// read), counted VMCNT(6) one-tile-deep cover, T5 setprio, 0-conflict b128
// geometry (LDS[row][c] = global chunk c^(row&7), pre-swizzled global src).
// ---------------------------------------------------------------------------
#define BM 256
#define BN 128
#define BK 128
#define KTILES (DDIM / BK)

__global__ __launch_bounds__(512, 2) void gemm_rowsum(
    const unsigned char* __restrict__ z1b,
    const unsigned char* __restrict__ z2b,
    float* __restrict__ partial)
{
  __shared__ __align__(16) unsigned char As[2][BM * BK];   // 2 x 32 KiB
  __shared__ __align__(16) unsigned char Bs[2][BN * BK];   // 2 x 16 KiB

  const int bid = blockIdx.x;
  const int bi = bid >> 6;          // 32 row-blocks
  const int bj = bid & 63;          // 64 col-blocks
  const int brow = bi * BM;
  const int bcol = bj * BN;
  const int t = threadIdx.x;
  const int w = t >> 6;             // wave 0..7
  const int lane = t & 63;
  const int wr = w >> 1;            // 0..3: A rows wr*64
  const int wc = w & 1;             // 0..1: B cols wc*64
  const int lcol = lane & 15;
  const int lgrp = lane >> 4;       // 0..3
  const int l7 = lcol & 7;
  const int sr = lane >> 3;         // stage: row within 8-row slab (0..7)
  const int sc = lane & 7;          // stage: 16B chunk (0..7)
  const int ssw = (sc ^ sr) << 4;   // pre-swizzled global byte offset

  f32x4 acc[4][4];
  #pragma unroll
  for (int i = 0; i < 4; ++i)
    #pragma unroll
    for (int j = 0; j < 4; ++j)
      acc[i][j] = (f32x4){0.f, 0.f, 0.f, 0.f};

  // ---- staging: slab = 8 rows x 128B = 1KB per gload; 4 A + 2 B per wave
#define STAGE_A(S, BUF, K0)                                                   \
  gload_lds16(z1b + (size_t)(brow + (w*4 + (S))*8 + sr) * DDIM + (K0) + ssw,  \
              &As[BUF][(w*4 + (S)) * 1024])
#define STAGE_B(S, BUF, K0)                                                   \
  gload_lds16(z2b + (size_t)(bcol + (w*2 + (S))*8 + sr) * DDIM + (K0) + ssw,  \
              &Bs[BUF][(w*2 + (S)) * 1024])

  // ---- fragment read: two b128 per operand, 0-conflict geometry,
  //      elementwise assembly (R7-proven: SROA-safe, no scratch) ----
#define RDFRAG(DST, ARR, ROWB)                                                \
  do {                                                                        \
    const int rb_ = (ROWB);                                                   \
    i32x4 lo_ = *(const i32x4*)&ARR[rb_*128 + ((lgrp)     ^ l7)*16];          \
    i32x4 hi_ = *(const i32x4*)&ARR[rb_*128 + ((4 + lgrp) ^ l7)*16];          \
    DST[0]=lo_[0]; DST[1]=lo_[1]; DST[2]=lo_[2]; DST[3]=lo_[3];               \
    DST[4]=hi_[0]; DST[5]=hi_[1]; DST[6]=hi_[2]; DST[7]=hi_[3];               \
  } while (0)

#define RA(MT, BUF, DST) RDFRAG(DST, As[BUF], wr*64 + (MT)*16 + lcol)
#define RB(NT, BUF, DST) RDFRAG(DST, Bs[BUF], wc*64 + (NT)*16 + lcol)

#define MF(MT, NT, AA, BB)                                                    \
  acc[MT][NT] = __builtin_amdgcn_mfma_scale_f32_16x16x128_f8f6f4(             \
      AA, BB, acc[MT][NT], 0, 0, 0, SCALE1, 0, SCALE1)

  // prologue: stage tile 0 -> buf0, tile 1 -> buf1; counted wait for tile 0
  #pragma unroll
  for (int s = 0; s < 4; ++s) STAGE_A(s, 0, 0);
  STAGE_B(0, 0, 0); STAGE_B(1, 0, 0);
  #pragma unroll
  for (int s = 0; s < 4; ++s) STAGE_A(s, 1, BK);
  STAGE_B(0, 1, BK); STAGE_B(1, 1, BK);
  VMCNT(6);          // tile 0's 6 loads landed; tile 1's stay in flight
  SBAR();

  i32x8 am0, am1, am2, am3, bn0, bn1, bn2, bn3;

  for (int kt = 0; kt < KTILES; ++kt) {
    const int cur = kt & 1;
    const int k2 = (kt + 2) * BK;
    const bool pf2 = (kt + 2 < KTILES);

    // ---- P1: read A m0..3 (8 b128, all As[cur] reads) + B n0,n1; 8 MFMA --
    RA(0, cur, am0); RA(1, cur, am1); RA(2, cur, am2); RA(3, cur, am3);
    RB(0, cur, bn0); RB(1, cur, bn1);
    SBAR();
    PRIO(1);
    MF(0,0,am0,bn0); MF(1,1,am1,bn1); MF(2,0,am2,bn0); MF(3,1,am3,bn1);
    MF(0,1,am0,bn1); MF(1,0,am1,bn0); MF(2,1,am2,bn1); MF(3,0,am3,bn0);
    PRIO(0);
    SBAR();

    // ---- P2: read B n2,n3 (last Bs[cur] reads); stage next-next A
    //      (As[cur] reads finished before P1's barriers); 4 MFMA ----
    RB(2, cur, bn2); RB(3, cur, bn3);
    if (pf2) { STAGE_A(0, cur, k2); STAGE_A(1, cur, k2);
               STAGE_A(2, cur, k2); STAGE_A(3, cur, k2); }
    SBAR();
    PRIO(1);
    MF(0,2,am0,bn2); MF(1,2,am1,bn2); MF(2,2,am2,bn2); MF(3,2,am3,bn2);
    PRIO(0);
    SBAR();

    // ---- P3: stage next-next B (Bs[cur] reads 2 barriers back); 4 MFMA;
    //      counted tile-boundary wait ----
    if (pf2) { STAGE_B(0, cur, k2); STAGE_B(1, cur, k2); }
    PRIO(1);
    MF(0,3,am0,bn3); MF(1,3,am1,bn3); MF(2,3,am2,bn3); MF(3,3,am3,bn3);
    PRIO(0);
    if (pf2)                   VMCNT(6);   // kt+1 ready; kt+2 in flight
    else if (kt + 1 < KTILES)  VMCNT(0);   // kt==KTILES-2: drain last tile
    SBAR();
  }

  // ---- epilogue: exp + per-row sum over this block's 128 cols ----
  // C/D layout (shape-determined): col = lane&15, row = lgrp*4 + reg.
  float* rs = (float*)&As[0][0];   // [2][256] f32, aliased (loads drained)
  #pragma unroll
  for (int mt = 0; mt < 4; ++mt) {
    #pragma unroll
    for (int r = 0; r < 4; ++r) {
      float s = __expf(acc[mt][0][r]) + __expf(acc[mt][1][r])
              + __expf(acc[mt][2][r]) + __expf(acc[mt][3][r]);
      s += __shfl_xor(s, 1);
      s += __shfl_xor(s, 2);
      s += __shfl_xor(s, 4);
      s += __shfl_xor(s, 8);
      if (lcol == 0)
        rs[wc * 256 + wr * 64 + mt * 16 + lgrp * 4 + r] = s;
    }
  }
  __syncthreads();
  if (t < 256)
    partial[(size_t)bj * NROW + brow + t] = rs[t] + rs[256 + t];
}

// ---------------------------------------------------------------------------
// Kernel 3: per-row loss = log(sum of 64 partials) - diag; block partial sums.
// ---------------------------------------------------------------------------
__global__ __launch_bounds__(256) void rowloss(
    const float* __restrict__ partial, const float* __restrict__ diag,
    float* __restrict__ blocksum)
{
  const int i = blockIdx.x * 256 + threadIdx.x;
  float s = 0.f;
  #pragma unroll 8
  for (int b = 0; b < 64; ++b) s += partial[(size_t)b * NROW + i];
  float loss = logf(s) - diag[i];
  #pragma unroll
  for (int m = 1; m < 64; m <<= 1) loss += __shfl_xor(loss, m);
  __shared__ float red[4];
  if ((threadIdx.x & 63) == 0) red[threadIdx.x >> 6] = loss;
  __syncthreads();
  if (threadIdx.x == 0)
    blocksum[blockIdx.x] = red[0] + red[1] + red[2] + red[3];
}

__global__ void finalize(const float* __restrict__ blocksum,
                         float* __restrict__ out)
{
  float s = (threadIdx.x < 32) ? blocksum[threadIdx.x] : 0.f;
  #pragma unroll
  for (int m = 1; m < 64; m <<= 1) s += __shfl_xor(s, m);
  if (threadIdx.x == 0) out[0] = s * (1.0f / NROW);
}

// ---------------------------------------------------------------------------
extern "C" void kernel_launch(void* const* d_in, const int* in_sizes, int n_in,
                              void* d_out, int out_size, void* d_ws, size_t ws_size,
                              hipStream_t stream) {
  const float* v1 = (const float*)d_in[0];
  const float* v2 = (const float*)d_in[1];
  float* out = (float*)d_out;

  char* ws = (char*)d_ws;
  // layout: z1 (8MB fp8) | z2 (8MB fp8) | diag (32KB) | partial (2MB) | bsum
  unsigned char* z1 = (unsigned char*)ws;
  unsigned char* z2 = (unsigned char*)(ws + (size_t)NROW * DDIM);
  float* diag = (float*)(ws + (size_t)NROW * DDIM * 2);
  float* partial = (float*)(ws + (size_t)NROW * DDIM * 2 + (size_t)NROW * 4);
  float* blocksum = (float*)(ws + (size_t)NROW * DDIM * 2 + (size_t)NROW * 4
                             + (size_t)64 * NROW * 4);

  normalize_diag<<<NROW, 256, 0, stream>>>(v1, v2, (unsigned*)z1, (unsigned*)z2,
                                           diag);
  gemm_rowsum<<<(NROW / BM) * (NROW / BN), 512, 0, stream>>>(z1, z2, partial);
  rowloss<<<NROW / 256, 256, 0, stream>>>(partial, diag, blocksum);
  finalize<<<1, 64, 0, stream>>>(blocksum, out);
}

// Round 11
// 408.006 us; speedup vs baseline: 1.5770x; 1.0041x over previous
//
#include <hip/hip_runtime.h>
#include <hip/hip_bf16.h>

#define NROW 8192
#define DDIM 1024          // bytes per fp8 row
#define TINV 2.0f          // 1 / TEMPERATURE
#define SCALE1 0x7F7F7F7F  // e8m0 = 127 in every byte -> scale 1.0

typedef __attribute__((ext_vector_type(4))) float f32x4;
typedef __attribute__((ext_vector_type(4))) int   i32x4;
typedef __attribute__((ext_vector_type(8))) int   i32x8;

__device__ __forceinline__ void gload_lds16(const void* g, void* l) {
  __builtin_amdgcn_global_load_lds(
      (const __attribute__((address_space(1))) void*)g,
      (__attribute__((address_space(3))) void*)l, 16, 0, 0);
}

#define SBAR()  __builtin_amdgcn_s_barrier()
#define PRIO(x) __builtin_amdgcn_s_setprio(x)
#define VMCNT(N) asm volatile("s_waitcnt vmcnt(" #N ")" ::: "memory")

// ---- manual f32 -> fp8 e4m3fn (OCP), RNE, saturating ----
__device__ __forceinline__ unsigned f2fp8(float x) {
  unsigned b = __float_as_uint(x);
  unsigned sgn = (b >> 24) & 0x80u;
  float af = __uint_as_float(b & 0x7FFFFFFFu);
  if (af >= 448.0f) return sgn | 0x7Eu;
  if (af < 0.015625f) {
    unsigned q = (unsigned)__float2int_rn(af * 512.0f);
    return sgn | q;
  }
  unsigned ab = b & 0x7FFFFFFFu;
  unsigned m  = ab & 0x7FFFFFu;
  unsigned m3 = m >> 20;
  unsigned rem = m & 0xFFFFFu;
  unsigned rnd = (rem > 0x80000u) || (rem == 0x80000u && (m3 & 1u));
  unsigned e  = (ab >> 23) - 120u;
  return sgn | ((e << 3) + m3 + rnd);
}

// ---------------------------------------------------------------------------
// Kernel 1: per-row L2 norms, diag (fp32-exact), fp8 normalized copies
// (z1 pre-scaled by 1/T; power-of-2 scale = exact).
// ---------------------------------------------------------------------------
__global__ __launch_bounds__(256) void normalize_diag(
    const float* __restrict__ v1, const float* __restrict__ v2,
    unsigned* __restrict__ z1, unsigned* __restrict__ z2,
    float* __restrict__ diag)
{
  const int row = blockIdx.x;
  const int t = threadIdx.x;
  const float4 a = ((const float4*)(v1 + (size_t)row * 1024))[t];
  const float4 b = ((const float4*)(v2 + (size_t)row * 1024))[t];
  float s1 = a.x*a.x + a.y*a.y + a.z*a.z + a.w*a.w;
  float s2 = b.x*b.x + b.y*b.y + b.z*b.z + b.w*b.w;
  float sd = a.x*b.x + a.y*b.y + a.z*b.z + a.w*b.w;
  #pragma unroll
  for (int m = 1; m < 64; m <<= 1) {
    s1 += __shfl_xor(s1, m);
    s2 += __shfl_xor(s2, m);
    sd += __shfl_xor(sd, m);
  }
  __shared__ float red[3][4];
  const int w = t >> 6;
  if ((t & 63) == 0) { red[0][w] = s1; red[1][w] = s2; red[2][w] = sd; }
  __syncthreads();
  s1 = red[0][0] + red[0][1] + red[0][2] + red[0][3];
  s2 = red[1][0] + red[1][1] + red[1][2] + red[1][3];
  sd = red[2][0] + red[2][1] + red[2][2] + red[2][3];
  const float i1 = 1.0f / fmaxf(sqrtf(s1), 1e-12f);
  const float i2 = 1.0f / fmaxf(sqrtf(s2), 1e-12f);
  if (t == 0) diag[row] = sd * i1 * i2 * TINV;
  const float sc1 = i1 * TINV;
  unsigned o1 = f2fp8(a.x*sc1) | (f2fp8(a.y*sc1) << 8)
              | (f2fp8(a.z*sc1) << 16) | (f2fp8(a.w*sc1) << 24);
  unsigned o2 = f2fp8(b.x*i2)  | (f2fp8(b.y*i2)  << 8)
              | (f2fp8(b.z*i2) << 16) | (f2fp8(b.w*i2)  << 24);
  z1[(size_t)row * 256 + t] = o1;
  z2[(size_t)row * 256 + t] = o2;
}

// ---------------------------------------------------------------------------
// Kernel 2: 256x128-tile MX-fp8 GEMM (sim = z1*z2^T) + fused exp-rowsum.
// Identical to R10 except __launch_bounds__(512, 1): the (512,2) bound
// capped the allocator at 128 VGPR/wave (observed: VGPR_Count==128 in all
// three spilling rounds) while the scaled-MFMA working set needs ~160 arch
// VGPRs (acc can't be relieved to AGPRs). LDS 96 KiB -> 1 block/CU anyway,
// so the looser bound costs no occupancy.
// 8 waves in a 4x2 grid, 64x64 per wave (acc=64), BK=128 bytes, counted
// VMCNT(6) one-tile-deep, T5 setprio, 0-conflict b128 geometry
// (LDS[row][c] = global chunk c^(row&7), pre-swizzled global src).
// ---------------------------------------------------------------------------
#define BM 256
#define BN 128
#define BK 128
#define KTILES (DDIM / BK)

__global__ __launch_bounds__(512, 1) void gemm_rowsum(
    const unsigned char* __restrict__ z1b,
    const unsigned char* __restrict__ z2b,
    float* __restrict__ partial)
{
  __shared__ __align__(16) unsigned char As[2][BM * BK];   // 2 x 32 KiB
  __shared__ __align__(16) unsigned char Bs[2][BN * BK];   // 2 x 16 KiB

  const int bid = blockIdx.x;
  const int bi = bid >> 6;          // 32 row-blocks
  const int bj = bid & 63;          // 64 col-blocks
  const int brow = bi * BM;
  const int bcol = bj * BN;
  const int t = threadIdx.x;
  const int w = t >> 6;             // wave 0..7
  const int lane = t & 63;
  const int wr = w >> 1;            // 0..3: A rows wr*64
  const int wc = w & 1;             // 0..1: B cols wc*64
  const int lcol = lane & 15;
  const int lgrp = lane >> 4;       // 0..3
  const int l7 = lcol & 7;
  const int sr = lane >> 3;         // stage: row within 8-row slab (0..7)
  const int sc = lane & 7;          // stage: 16B chunk (0..7)
  const int ssw = (sc ^ sr) << 4;   // pre-swizzled global byte offset

  f32x4 acc[4][4];
  #pragma unroll
  for (int i = 0; i < 4; ++i)
    #pragma unroll
    for (int j = 0; j < 4; ++j)
      acc[i][j] = (f32x4){0.f, 0.f, 0.f, 0.f};

  // ---- staging: slab = 8 rows x 128B = 1KB per gload; 4 A + 2 B per wave
#define STAGE_A(S, BUF, K0)                                                   \
  gload_lds16(z1b + (size_t)(brow + (w*4 + (S))*8 + sr) * DDIM + (K0) + ssw,  \
              &As[BUF][(w*4 + (S)) * 1024])
#define STAGE_B(S, BUF, K0)                                                   \
  gload_lds16(z2b + (size_t)(bcol + (w*2 + (S))*8 + sr) * DDIM + (K0) + ssw,  \
              &Bs[BUF][(w*2 + (S)) * 1024])

  // ---- fragment read: two b128 per operand, 0-conflict geometry,
  //      elementwise assembly (R7-proven: SROA-safe, no scratch) ----
#define RDFRAG(DST, ARR, ROWB)                                                \
  do {                                                                        \
    const int rb_ = (ROWB);                                                   \
    i32x4 lo_ = *(const i32x4*)&ARR[rb_*128 + ((lgrp)     ^ l7)*16];          \
    i32x4 hi_ = *(const i32x4*)&ARR[rb_*128 + ((4 + lgrp) ^ l7)*16];          \
    DST[0]=lo_[0]; DST[1]=lo_[1]; DST[2]=lo_[2]; DST[3]=lo_[3];               \
    DST[4]=hi_[0]; DST[5]=hi_[1]; DST[6]=hi_[2]; DST[7]=hi_[3];               \
  } while (0)

#define RA(MT, BUF, DST) RDFRAG(DST, As[BUF], wr*64 + (MT)*16 + lcol)
#define RB(NT, BUF, DST) RDFRAG(DST, Bs[BUF], wc*64 + (NT)*16 + lcol)

#define MF(MT, NT, AA, BB)                                                    \
  acc[MT][NT] = __builtin_amdgcn_mfma_scale_f32_16x16x128_f8f6f4(             \
      AA, BB, acc[MT][NT], 0, 0, 0, SCALE1, 0, SCALE1)

  // prologue: stage tile 0 -> buf0, tile 1 -> buf1; counted wait for tile 0
  #pragma unroll
  for (int s = 0; s < 4; ++s) STAGE_A(s, 0, 0);
  STAGE_B(0, 0, 0); STAGE_B(1, 0, 0);
  #pragma unroll
  for (int s = 0; s < 4; ++s) STAGE_A(s, 1, BK);
  STAGE_B(0, 1, BK); STAGE_B(1, 1, BK);
  VMCNT(6);          // tile 0's 6 loads landed; tile 1's stay in flight
  SBAR();

  i32x8 am0, am1, am2, am3, bn0, bn1, bn2, bn3;

  for (int kt = 0; kt < KTILES; ++kt) {
    const int cur = kt & 1;
    const int k2 = (kt + 2) * BK;
    const bool pf2 = (kt + 2 < KTILES);

    // ---- P1: read A m0..3 (8 b128, all As[cur] reads) + B n0,n1; 8 MFMA --
    RA(0, cur, am0); RA(1, cur, am1); RA(2, cur, am2); RA(3, cur, am3);
    RB(0, cur, bn0); RB(1, cur, bn1);
    SBAR();
    PRIO(1);
    MF(0,0,am0,bn0); MF(1,1,am1,bn1); MF(2,0,am2,bn0); MF(3,1,am3,bn1);
    MF(0,1,am0,bn1); MF(1,0,am1,bn0); MF(2,1,am2,bn1); MF(3,0,am3,bn0);
    PRIO(0);
    SBAR();

    // ---- P2: read B n2,n3 (last Bs[cur] reads); stage next-next A
    //      (As[cur] reads finished before P1's barriers); 4 MFMA ----
    RB(2, cur, bn2); RB(3, cur, bn3);
    if (pf2) { STAGE_A(0, cur, k2); STAGE_A(1, cur, k2);
               STAGE_A(2, cur, k2); STAGE_A(3, cur, k2); }
    SBAR();
    PRIO(1);
    MF(0,2,am0,bn2); MF(1,2,am1,bn2); MF(2,2,am2,bn2); MF(3,2,am3,bn2);
    PRIO(0);
    SBAR();

    // ---- P3: stage next-next B (Bs[cur] reads 2 barriers back); 4 MFMA;
    //      counted tile-boundary wait ----
    if (pf2) { STAGE_B(0, cur, k2); STAGE_B(1, cur, k2); }
    PRIO(1);
    MF(0,3,am0,bn3); MF(1,3,am1,bn3); MF(2,3,am2,bn3); MF(3,3,am3,bn3);
    PRIO(0);
    if (pf2)                   VMCNT(6);   // kt+1 ready; kt+2 in flight
    else if (kt + 1 < KTILES)  VMCNT(0);   // kt==KTILES-2: drain last tile
    SBAR();
  }

  // ---- epilogue: exp + per-row sum over this block's 128 cols ----
  // C/D layout (shape-determined): col = lane&15, row = lgrp*4 + reg.
  float* rs = (float*)&As[0][0];   // [2][256] f32, aliased (loads drained)
  #pragma unroll
  for (int mt = 0; mt < 4; ++mt) {
    #pragma unroll
    for (int r = 0; r < 4; ++r) {
      float s = __expf(acc[mt][0][r]) + __expf(acc[mt][1][r])
              + __expf(acc[mt][2][r]) + __expf(acc[mt][3][r]);
      s += __shfl_xor(s, 1);
      s += __shfl_xor(s, 2);
      s += __shfl_xor(s, 4);
      s += __shfl_xor(s, 8);
      if (lcol == 0)
        rs[wc * 256 + wr * 64 + mt * 16 + lgrp * 4 + r] = s;
    }
  }
  __syncthreads();
  if (t < 256)
    partial[(size_t)bj * NROW + brow + t] = rs[t] + rs[256 + t];
}

// ---------------------------------------------------------------------------
// Kernel 3: per-row loss = log(sum of 64 partials) - diag; block partial sums.
// ---------------------------------------------------------------------------
__global__ __launch_bounds__(256) void rowloss(
    const float* __restrict__ partial, const float* __restrict__ diag,
    float* __restrict__ blocksum)
{
  const int i = blockIdx.x * 256 + threadIdx.x;
  float s = 0.f;
  #pragma unroll 8
  for (int b = 0; b < 64; ++b) s += partial[(size_t)b * NROW + i];
  float loss = logf(s) - diag[i];
  #pragma unroll
  for (int m = 1; m < 64; m <<= 1) loss += __shfl_xor(loss, m);
  __shared__ float red[4];
  if ((threadIdx.x & 63) == 0) red[threadIdx.x >> 6] = loss;
  __syncthreads();
  if (threadIdx.x == 0)
    blocksum[blockIdx.x] = red[0] + red[1] + red[2] + red[3];
}

__global__ void finalize(const float* __restrict__ blocksum,
                         float* __restrict__ out)
{
  float s = (threadIdx.x < 32) ? blocksum[threadIdx.x] : 0.f;
  #pragma unroll
  for (int m = 1; m < 64; m <<= 1) s += __shfl_xor(s, m);
  if (threadIdx.x == 0) out[0] = s * (1.0f / NROW);
}

// ---------------------------------------------------------------------------
extern "C" void kernel_launch(void* const* d_in, const int* in_sizes, int n_in,
                              void* d_out, int out_size, void* d_ws, size_t ws_size,
                              hipStream_t stream) {
  const float* v1 = (const float*)d_in[0];
  const float* v2 = (const float*)d_in[1];
  float* out = (float*)d_out;

  char* ws = (char*)d_ws;
  // layout: z1 (8MB fp8) | z2 (8MB fp8) | diag (32KB) | partial (2MB) | bsum
  unsigned char* z1 = (unsigned char*)ws;
  unsigned char* z2 = (unsigned char*)(ws + (size_t)NROW * DDIM);
  float* diag = (float*)(ws + (size_t)NROW * DDIM * 2);
  float* partial = (float*)(ws + (size_t)NROW * DDIM * 2 + (size_t)NROW * 4);
  float* blocksum = (float*)(ws + (size_t)NROW * DDIM * 2 + (size_t)NROW * 4
                             + (size_t)64 * NROW * 4);

  normalize_diag<<<NROW, 256, 0, stream>>>(v1, v2, (unsigned*)z1, (unsigned*)z2,
                                           diag);
  gemm_rowsum<<<(NROW / BM) * (NROW / BN), 512, 0, stream>>>(z1, z2, partial);
  rowloss<<<NROW / 256, 256, 0, stream>>>(partial, diag, blocksum);
  finalize<<<1, 64, 0, stream>>>(blocksum, out);
}

// Round 12
// 390.995 us; speedup vs baseline: 1.6456x; 1.0435x over previous
//
#include <hip/hip_runtime.h>
#include <hip/hip_bf16.h>

#define NROW 8192
#define DDIM 1024          // bytes per fp8 row
#define TINV 2.0f          // 1 / TEMPERATURE
#define SCALE1 0x7F7F7F7F  // e8m0 = 127 in every byte -> scale 1.0

typedef __attribute__((ext_vector_type(4))) float f32x4;
typedef __attribute__((ext_vector_type(4))) int   i32x4;
typedef __attribute__((ext_vector_type(8))) int   i32x8;

__device__ __forceinline__ void gload_lds16(const void* g, void* l) {
  __builtin_amdgcn_global_load_lds(
      (const __attribute__((address_space(1))) void*)g,
      (__attribute__((address_space(3))) void*)l, 16, 0, 0);
}

#define SBAR()  __builtin_amdgcn_s_barrier()
#define PRIO(x) __builtin_amdgcn_s_setprio(x)
#define VMCNT(N) asm volatile("s_waitcnt vmcnt(" #N ")" ::: "memory")

// ---- manual f32 -> fp8 e4m3fn (OCP), RNE, saturating ----
__device__ __forceinline__ unsigned f2fp8(float x) {
  unsigned b = __float_as_uint(x);
  unsigned sgn = (b >> 24) & 0x80u;
  float af = __uint_as_float(b & 0x7FFFFFFFu);
  if (af >= 448.0f) return sgn | 0x7Eu;
  if (af < 0.015625f) {
    unsigned q = (unsigned)__float2int_rn(af * 512.0f);
    return sgn | q;
  }
  unsigned ab = b & 0x7FFFFFFFu;
  unsigned m  = ab & 0x7FFFFFu;
  unsigned m3 = m >> 20;
  unsigned rem = m & 0xFFFFFu;
  unsigned rnd = (rem > 0x80000u) || (rem == 0x80000u && (m3 & 1u));
  unsigned e  = (ab >> 23) - 120u;
  return sgn | ((e << 3) + m3 + rnd);
}

// ---------------------------------------------------------------------------
// Kernel 1: per-row L2 norms, diag (fp32-exact), fp8 normalized copies
// (z1 pre-scaled by 1/T; power-of-2 scale = exact).
// ---------------------------------------------------------------------------
__global__ __launch_bounds__(256) void normalize_diag(
    const float* __restrict__ v1, const float* __restrict__ v2,
    unsigned* __restrict__ z1, unsigned* __restrict__ z2,
    float* __restrict__ diag)
{
  const int row = blockIdx.x;
  const int t = threadIdx.x;
  const float4 a = ((const float4*)(v1 + (size_t)row * 1024))[t];
  const float4 b = ((const float4*)(v2 + (size_t)row * 1024))[t];
  float s1 = a.x*a.x + a.y*a.y + a.z*a.z + a.w*a.w;
  float s2 = b.x*b.x + b.y*b.y + b.z*b.z + b.w*b.w;
  float sd = a.x*b.x + a.y*b.y + a.z*b.z + a.w*b.w;
  #pragma unroll
  for (int m = 1; m < 64; m <<= 1) {
    s1 += __shfl_xor(s1, m);
    s2 += __shfl_xor(s2, m);
    sd += __shfl_xor(sd, m);
  }
  __shared__ float red[3][4];
  const int w = t >> 6;
  if ((t & 63) == 0) { red[0][w] = s1; red[1][w] = s2; red[2][w] = sd; }
  __syncthreads();
  s1 = red[0][0] + red[0][1] + red[0][2] + red[0][3];
  s2 = red[1][0] + red[1][1] + red[1][2] + red[1][3];
  sd = red[2][0] + red[2][1] + red[2][2] + red[2][3];
  const float i1 = 1.0f / fmaxf(sqrtf(s1), 1e-12f);
  const float i2 = 1.0f / fmaxf(sqrtf(s2), 1e-12f);
  if (t == 0) diag[row] = sd * i1 * i2 * TINV;
  const float sc1 = i1 * TINV;
  unsigned o1 = f2fp8(a.x*sc1) | (f2fp8(a.y*sc1) << 8)
              | (f2fp8(a.z*sc1) << 16) | (f2fp8(a.w*sc1) << 24);
  unsigned o2 = f2fp8(b.x*i2)  | (f2fp8(b.y*i2)  << 8)
              | (f2fp8(b.z*i2) << 16) | (f2fp8(b.w*i2)  << 24);
  z1[(size_t)row * 256 + t] = o1;
  z2[(size_t)row * 256 + t] = o2;
}

// ---------------------------------------------------------------------------
// Kernel 2: 256x128-tile MX-fp8 GEMM (sim = z1*z2^T) + fused exp-rowsum.
// The 512-thread VGPR cap is 128/wave (R8-R11: bound changes are no-ops),
// so this uses R7's PROVEN zero-spill fragment lifecycle: only TWO A-frags
// live at any time (am0,am1 reused for m2,m3 in P3). Peak live ~=
// acc 64 + am 16 + bn 32 + addr ~= 120 <= 128.
// 8 waves (4M x 2N), 64x64 per wave, BK=128 bytes, LDS 96 KiB (1 block/CU),
// counted VMCNT(6) one-tile-deep, T5 setprio, 0-conflict b128 geometry
// (LDS[row][c] = global chunk c^(row&7), pre-swizzled global src).
// Schedule = R7's verbatim: P1{RA m01,RB n01|4MF} P2{RB n23|4MF}
// P3{RA m23 reuse, stage B(kt+2)|4MF} P4{stage A(kt+2)|4MF|VMCNT(6)}.
// ---------------------------------------------------------------------------
#define BM 256
#define BN 128
#define BK 128
#define KTILES (DDIM / BK)

__global__ __launch_bounds__(512, 1) void gemm_rowsum(
    const unsigned char* __restrict__ z1b,
    const unsigned char* __restrict__ z2b,
    float* __restrict__ partial)
{
  __shared__ __align__(16) unsigned char As[2][BM * BK];   // 2 x 32 KiB
  __shared__ __align__(16) unsigned char Bs[2][BN * BK];   // 2 x 16 KiB

  const int bid = blockIdx.x;
  const int bi = bid >> 6;          // 32 row-blocks
  const int bj = bid & 63;          // 64 col-blocks
  const int brow = bi * BM;
  const int bcol = bj * BN;
  const int t = threadIdx.x;
  const int w = t >> 6;             // wave 0..7
  const int lane = t & 63;
  const int wr = w >> 1;            // 0..3: A rows wr*64
  const int wc = w & 1;             // 0..1: B cols wc*64
  const int lcol = lane & 15;
  const int lgrp = lane >> 4;       // 0..3
  const int l7 = lcol & 7;
  const int sr = lane >> 3;         // stage: row within 8-row slab (0..7)
  const int sc = lane & 7;          // stage: 16B chunk (0..7)
  const int ssw = (sc ^ sr) << 4;   // pre-swizzled global byte offset

  f32x4 acc[4][4];
  #pragma unroll
  for (int i = 0; i < 4; ++i)
    #pragma unroll
    for (int j = 0; j < 4; ++j)
      acc[i][j] = (f32x4){0.f, 0.f, 0.f, 0.f};

  // ---- staging: slab = 8 rows x 128B = 1KB per gload; 4 A + 2 B per wave
#define STAGE_A(S, BUF, K0)                                                   \
  gload_lds16(z1b + (size_t)(brow + (w*4 + (S))*8 + sr) * DDIM + (K0) + ssw,  \
              &As[BUF][(w*4 + (S)) * 1024])
#define STAGE_B(S, BUF, K0)                                                   \
  gload_lds16(z2b + (size_t)(bcol + (w*2 + (S))*8 + sr) * DDIM + (K0) + ssw,  \
              &Bs[BUF][(w*2 + (S)) * 1024])

  // ---- fragment read: two b128 per operand, 0-conflict geometry,
  //      elementwise assembly (R7-proven: SROA-safe, no scratch) ----
#define RDFRAG(DST, ARR, ROWB)                                                \
  do {                                                                        \
    const int rb_ = (ROWB);                                                   \
    i32x4 lo_ = *(const i32x4*)&ARR[rb_*128 + ((lgrp)     ^ l7)*16];          \
    i32x4 hi_ = *(const i32x4*)&ARR[rb_*128 + ((4 + lgrp) ^ l7)*16];          \
    DST[0]=lo_[0]; DST[1]=lo_[1]; DST[2]=lo_[2]; DST[3]=lo_[3];               \
    DST[4]=hi_[0]; DST[5]=hi_[1]; DST[6]=hi_[2]; DST[7]=hi_[3];               \
  } while (0)

#define RA(MT, BUF, DST) RDFRAG(DST, As[BUF], wr*64 + (MT)*16 + lcol)
#define RB(NT, BUF, DST) RDFRAG(DST, Bs[BUF], wc*64 + (NT)*16 + lcol)

#define MF(MT, NT, AA, BB)                                                    \
  acc[MT][NT] = __builtin_amdgcn_mfma_scale_f32_16x16x128_f8f6f4(             \
      AA, BB, acc[MT][NT], 0, 0, 0, SCALE1, 0, SCALE1)

  // prologue: stage tile 0 -> buf0, tile 1 -> buf1; counted wait for tile 0
  #pragma unroll
  for (int s = 0; s < 4; ++s) STAGE_A(s, 0, 0);
  STAGE_B(0, 0, 0); STAGE_B(1, 0, 0);
  #pragma unroll
  for (int s = 0; s < 4; ++s) STAGE_A(s, 1, BK);
  STAGE_B(0, 1, BK); STAGE_B(1, 1, BK);
  VMCNT(6);          // tile 0's 6 loads landed; tile 1's stay in flight
  SBAR();

  i32x8 am0, am1, bn0, bn1, bn2, bn3;   // only 2 A-frags live (R7 envelope)

  for (int kt = 0; kt < KTILES; ++kt) {
    const int cur = kt & 1;
    const int k2 = (kt + 2) * BK;
    const bool pf2 = (kt + 2 < KTILES);

    // ---- P1: read A m0,m1 + B n0,n1; 4 MFMA ----
    RA(0, cur, am0); RA(1, cur, am1);
    RB(0, cur, bn0); RB(1, cur, bn1);
    SBAR();
    PRIO(1);
    MF(0,0,am0,bn0); MF(1,1,am1,bn1); MF(0,1,am0,bn1); MF(1,0,am1,bn0);
    PRIO(0);
    SBAR();

    // ---- P2: read B n2,n3 (last Bs[cur] reads); 4 MFMA ----
    RB(2, cur, bn2); RB(3, cur, bn3);
    SBAR();
    PRIO(1);
    MF(0,2,am0,bn2); MF(1,3,am1,bn3); MF(0,3,am0,bn3); MF(1,2,am1,bn2);
    PRIO(0);
    SBAR();

    // ---- P3: read A m2,m3 (reusing am0,am1; last As[cur] reads);
    //      stage next-next B (Bs[cur] drained: P2 reads + barrier); 4 MFMA --
    RA(2, cur, am0); RA(3, cur, am1);
    if (pf2) { STAGE_B(0, cur, k2); STAGE_B(1, cur, k2); }
    SBAR();
    PRIO(1);
    MF(2,2,am0,bn2); MF(3,3,am1,bn3); MF(2,3,am0,bn3); MF(3,2,am1,bn2);
    PRIO(0);
    SBAR();

    // ---- P4: stage next-next A (As[cur] drained: P3 reads + barrier);
    //      4 MFMA; counted tile-boundary wait ----
    if (pf2) { STAGE_A(0, cur, k2); STAGE_A(1, cur, k2);
               STAGE_A(2, cur, k2); STAGE_A(3, cur, k2); }
    PRIO(1);
    MF(2,0,am0,bn0); MF(3,1,am1,bn1); MF(2,1,am0,bn1); MF(3,0,am1,bn0);
    PRIO(0);
    if (pf2)                   VMCNT(6);   // kt+1 ready; kt+2 in flight
    else if (kt + 1 < KTILES)  VMCNT(0);   // kt==KTILES-2: drain last tile
    SBAR();
  }

  // ---- epilogue: exp + per-row sum over this block's 128 cols ----
  // C/D layout (shape-determined): col = lane&15, row = lgrp*4 + reg.
  float* rs = (float*)&As[0][0];   // [2][256] f32, aliased (loads drained)
  #pragma unroll
  for (int mt = 0; mt < 4; ++mt) {
    #pragma unroll
    for (int r = 0; r < 4; ++r) {
      float s = __expf(acc[mt][0][r]) + __expf(acc[mt][1][r])
              + __expf(acc[mt][2][r]) + __expf(acc[mt][3][r]);
      s += __shfl_xor(s, 1);
      s += __shfl_xor(s, 2);
      s += __shfl_xor(s, 4);
      s += __shfl_xor(s, 8);
      if (lcol == 0)
        rs[wc * 256 + wr * 64 + mt * 16 + lgrp * 4 + r] = s;
    }
  }
  __syncthreads();
  if (t < 256)
    partial[(size_t)bj * NROW + brow + t] = rs[t] + rs[256 + t];
}

// ---------------------------------------------------------------------------
// Kernel 3: per-row loss = log(sum of 64 partials) - diag; block partial sums.
// ---------------------------------------------------------------------------
__global__ __launch_bounds__(256) void rowloss(
    const float* __restrict__ partial, const float* __restrict__ diag,
    float* __restrict__ blocksum)
{
  const int i = blockIdx.x * 256 + threadIdx.x;
  float s = 0.f;
  #pragma unroll 8
  for (int b = 0; b < 64; ++b) s += partial[(size_t)b * NROW + i];
  float loss = logf(s) - diag[i];
  #pragma unroll
  for (int m = 1; m < 64; m <<= 1) loss += __shfl_xor(loss, m);
  __shared__ float red[4];
  if ((threadIdx.x & 63) == 0) red[threadIdx.x >> 6] = loss;
  __syncthreads();
  if (threadIdx.x == 0)
    blocksum[blockIdx.x] = red[0] + red[1] + red[2] + red[3];
}

__global__ void finalize(const float* __restrict__ blocksum,
                         float* __restrict__ out)
{
  float s = (threadIdx.x < 32) ? blocksum[threadIdx.x] : 0.f;
  #pragma unroll
  for (int m = 1; m < 64; m <<= 1) s += __shfl_xor(s, m);
  if (threadIdx.x == 0) out[0] = s * (1.0f / NROW);
}

// ---------------------------------------------------------------------------
extern "C" void kernel_launch(void* const* d_in, const int* in_sizes, int n_in,
                              void* d_out, int out_size, void* d_ws, size_t ws_size,
                              hipStream_t stream) {
  const float* v1 = (const float*)d_in[0];
  const float* v2 = (const float*)d_in[1];
  float* out = (float*)d_out;

  char* ws = (char*)d_ws;
  // layout: z1 (8MB fp8) | z2 (8MB fp8) | diag (32KB) | partial (2MB) | bsum
  unsigned char* z1 = (unsigned char*)ws;
  unsigned char* z2 = (unsigned char*)(ws + (size_t)NROW * DDIM);
  float* diag = (float*)(ws + (size_t)NROW * DDIM * 2);
  float* partial = (float*)(ws + (size_t)NROW * DDIM * 2 + (size_t)NROW * 4);
  float* blocksum = (float*)(ws + (size_t)NROW * DDIM * 2 + (size_t)NROW * 4
                             + (size_t)64 * NROW * 4);

  normalize_diag<<<NROW, 256, 0, stream>>>(v1, v2, (unsigned*)z1, (unsigned*)z2,
                                           diag);
  gemm_rowsum<<<(NROW / BM) * (NROW / BN), 512, 0, stream>>>(z1, z2, partial);
  rowloss<<<NROW / 256, 256, 0, stream>>>(partial, diag, blocksum);
  finalize<<<1, 64, 0, stream>>>(blocksum, out);
}